// Round 1
// baseline (1984.053 us; speedup 1.0000x reference)
//
#include <hip/hip_runtime.h>
#include <hip/hip_bf16.h>

// Problem constants (fixed by the reference)
#define NN 50000
#define EE 800000
#define ND 64
#define ED 32
#define HH 128

// ---------------------------------------------------------------------------
// Generic tiled fp32 GEMM: Y[M x Ncols] = X[M x K] @ W[Ncols x ldw(.T slice)] + opts
//   BIAS:  + bias[col]           (DEGB: bias[col] * deg[row])
//   CMAT:  + Cm[row][col]
// 64x64 tile, 256 threads, 4x4 per thread, KSTEP=32 staged in LDS.
// ---------------------------------------------------------------------------
template<int KSTEP, bool BIAS, bool CMAT, bool DEGB>
__global__ __launch_bounds__(256) void k_gemm(
    const float* __restrict__ X, int K,
    const float* __restrict__ W, int ldw,
    const float* __restrict__ bias,
    const float* __restrict__ Cm,
    const int* __restrict__ deg,
    float* __restrict__ Y, int M, int Ncols)
{
    __shared__ float Xs[64][KSTEP + 1];
    __shared__ float Ws[64][KSTEP + 1];
    const int m0 = blockIdx.x * 64;
    const int n0 = blockIdx.y * 64;
    const int tid = threadIdx.x;
    const int tx = tid & 15, ty = tid >> 4;

    float acc[4][4] = {};

    for (int k0 = 0; k0 < K; k0 += KSTEP) {
        // stage X tile (64 x KSTEP)
        for (int f = tid; f < 64 * KSTEP / 4; f += 256) {
            int r = f / (KSTEP / 4);
            int c4 = (f % (KSTEP / 4)) * 4;
            int gr = m0 + r;
            float4 v = make_float4(0.f, 0.f, 0.f, 0.f);
            if (gr < M)
                v = *reinterpret_cast<const float4*>(X + (size_t)gr * K + k0 + c4);
            Xs[r][c4 + 0] = v.x; Xs[r][c4 + 1] = v.y;
            Xs[r][c4 + 2] = v.z; Xs[r][c4 + 3] = v.w;
        }
        // stage W tile (64 x KSTEP); n0+r always < Ncols (Ncols % 64 == 0)
        for (int f = tid; f < 64 * KSTEP / 4; f += 256) {
            int r = f / (KSTEP / 4);
            int c4 = (f % (KSTEP / 4)) * 4;
            float4 v = *reinterpret_cast<const float4*>(W + (size_t)(n0 + r) * ldw + k0 + c4);
            Ws[r][c4 + 0] = v.x; Ws[r][c4 + 1] = v.y;
            Ws[r][c4 + 2] = v.z; Ws[r][c4 + 3] = v.w;
        }
        __syncthreads();
        #pragma unroll
        for (int kk = 0; kk < KSTEP; ++kk) {
            float a[4], b[4];
            #pragma unroll
            for (int i = 0; i < 4; ++i) a[i] = Xs[ty * 4 + i][kk];
            #pragma unroll
            for (int j = 0; j < 4; ++j) b[j] = Ws[tx * 4 + j][kk];
            #pragma unroll
            for (int i = 0; i < 4; ++i)
                #pragma unroll
                for (int j = 0; j < 4; ++j)
                    acc[i][j] += a[i] * b[j];
        }
        __syncthreads();
    }

    #pragma unroll
    for (int i = 0; i < 4; ++i) {
        int row = m0 + ty * 4 + i;
        if (row >= M) continue;
        #pragma unroll
        for (int j = 0; j < 4; ++j) {
            int col = n0 + tx * 4 + j;
            float v = acc[i][j];
            if (BIAS) v += DEGB ? bias[col] * (float)deg[row] : bias[col];
            if (CMAT) v += Cm[(size_t)row * Ncols + col];
            Y[(size_t)row * Ncols + col] = v;
        }
    }
}

// ---------------------------------------------------------------------------
// Fused GRU: ghh = h @ W_hh.T (3 gate accumulators per output col) + gate math.
// gi (= agg @ W_ih.T + b_ih) precomputed. Writes h_new.
// ---------------------------------------------------------------------------
__global__ __launch_bounds__(256) void k_gru(
    const float* __restrict__ hin, const float* __restrict__ Whh,
    const float* __restrict__ bhh, const float* __restrict__ gi,
    float* __restrict__ hout, int M)
{
    constexpr int KS = 32;
    __shared__ float Hs[64][KS + 1];
    __shared__ float Wr[64][KS + 1];
    __shared__ float Wz[64][KS + 1];
    __shared__ float Wn[64][KS + 1];
    const int m0 = blockIdx.x * 64;
    const int c0 = blockIdx.y * 64;
    const int tid = threadIdx.x;
    const int tx = tid & 15, ty = tid >> 4;

    float ar[4][4] = {}, az[4][4] = {}, an[4][4] = {};

    for (int k0 = 0; k0 < HH; k0 += KS) {
        for (int f = tid; f < 64 * KS / 4; f += 256) {
            int r = f / (KS / 4);
            int c4 = (f % (KS / 4)) * 4;
            int gr = m0 + r;
            float4 v = make_float4(0.f, 0.f, 0.f, 0.f);
            if (gr < M)
                v = *reinterpret_cast<const float4*>(hin + (size_t)gr * HH + k0 + c4);
            Hs[r][c4] = v.x; Hs[r][c4 + 1] = v.y; Hs[r][c4 + 2] = v.z; Hs[r][c4 + 3] = v.w;

            float4 w0 = *reinterpret_cast<const float4*>(Whh + (size_t)(c0 + r) * HH + k0 + c4);
            Wr[r][c4] = w0.x; Wr[r][c4 + 1] = w0.y; Wr[r][c4 + 2] = w0.z; Wr[r][c4 + 3] = w0.w;
            float4 w1 = *reinterpret_cast<const float4*>(Whh + (size_t)(HH + c0 + r) * HH + k0 + c4);
            Wz[r][c4] = w1.x; Wz[r][c4 + 1] = w1.y; Wz[r][c4 + 2] = w1.z; Wz[r][c4 + 3] = w1.w;
            float4 w2 = *reinterpret_cast<const float4*>(Whh + (size_t)(2 * HH + c0 + r) * HH + k0 + c4);
            Wn[r][c4] = w2.x; Wn[r][c4 + 1] = w2.y; Wn[r][c4 + 2] = w2.z; Wn[r][c4 + 3] = w2.w;
        }
        __syncthreads();
        #pragma unroll
        for (int kk = 0; kk < KS; ++kk) {
            float a[4], br[4], bz[4], bn[4];
            #pragma unroll
            for (int i = 0; i < 4; ++i) a[i] = Hs[ty * 4 + i][kk];
            #pragma unroll
            for (int j = 0; j < 4; ++j) {
                br[j] = Wr[tx * 4 + j][kk];
                bz[j] = Wz[tx * 4 + j][kk];
                bn[j] = Wn[tx * 4 + j][kk];
            }
            #pragma unroll
            for (int i = 0; i < 4; ++i)
                #pragma unroll
                for (int j = 0; j < 4; ++j) {
                    ar[i][j] += a[i] * br[j];
                    az[i][j] += a[i] * bz[j];
                    an[i][j] += a[i] * bn[j];
                }
        }
        __syncthreads();
    }

    #pragma unroll
    for (int i = 0; i < 4; ++i) {
        int row = m0 + ty * 4 + i;
        if (row >= M) continue;
        #pragma unroll
        for (int j = 0; j < 4; ++j) {
            int c = c0 + tx * 4 + j;
            float gr_ = gi[(size_t)row * 384 + c];
            float gz_ = gi[(size_t)row * 384 + HH + c];
            float gn_ = gi[(size_t)row * 384 + 2 * HH + c];
            float hr = ar[i][j] + bhh[c];
            float hz = az[i][j] + bhh[HH + c];
            float hn = an[i][j] + bhh[2 * HH + c];
            float r = 1.f / (1.f + expf(-(gr_ + hr)));
            float z = 1.f / (1.f + expf(-(gz_ + hz)));
            float n = tanhf(gn_ + r * hn);
            float hv = hin[(size_t)row * HH + c];
            hout[(size_t)row * HH + c] = (1.f - z) * n + z * hv;
        }
    }
}

// ---------------------------------------------------------------------------
// CSR build: histogram, scan (3 kernels), cursor copy, bucket scatter
// ---------------------------------------------------------------------------
__global__ void k_hist(const int* __restrict__ dst, int* __restrict__ deg, int n) {
    int e = blockIdx.x * 256 + threadIdx.x;
    if (e < n) atomicAdd(&deg[dst[e]], 1);
}

__global__ __launch_bounds__(1024) void k_scan_block(
    const int* __restrict__ deg, int* __restrict__ rp, int* __restrict__ bsum, int n)
{
    __shared__ int s[1024];
    int i = blockIdx.x * 1024 + threadIdx.x;
    s[threadIdx.x] = (i < n) ? deg[i] : 0;
    __syncthreads();
    for (int off = 1; off < 1024; off <<= 1) {
        int t = (threadIdx.x >= (unsigned)off) ? s[threadIdx.x - off] : 0;
        __syncthreads();
        s[threadIdx.x] += t;
        __syncthreads();
    }
    if (i < n) rp[i + 1] = s[threadIdx.x];
    if (threadIdx.x == 1023) bsum[blockIdx.x] = s[1023];
}

__global__ void k_scan_tops(int* bsum, int nb) {
    if (threadIdx.x == 0 && blockIdx.x == 0) {
        int run = 0;
        for (int b = 0; b < nb; ++b) { int v = bsum[b]; bsum[b] = run; run += v; }
    }
}

__global__ __launch_bounds__(1024) void k_scan_add(int* rp, const int* __restrict__ bsum, int n) {
    int i = blockIdx.x * 1024 + threadIdx.x;
    if (i < n) rp[i + 1] += bsum[blockIdx.x];
    if (i == 0) rp[0] = 0;
}

__global__ void k_cursor(const int* __restrict__ rp, int* __restrict__ cur, int n) {
    int i = blockIdx.x * 256 + threadIdx.x;
    if (i < n) cur[i] = rp[i];
}

__global__ void k_bucket(const int* __restrict__ src, const int* __restrict__ dst,
                         int* __restrict__ cur, int* __restrict__ eid,
                         int* __restrict__ ssrc, int n)
{
    int e = blockIdx.x * 256 + threadIdx.x;
    if (e < n) {
        int d = dst[e];
        int p = atomicAdd(&cur[d], 1);
        eid[p] = e;
        ssrc[p] = src[e];
    }
}

// ---------------------------------------------------------------------------
// Pull-reduce: out[d][:] = sum over CSR range of X[idx[j]][:]  (128 f32 cols)
// one wave per node; lane holds float2 (2 cols)
// ---------------------------------------------------------------------------
__global__ __launch_bounds__(256) void k_pull(
    const float* __restrict__ X, const int* __restrict__ idxarr,
    const int* __restrict__ rp, float* __restrict__ out, int n)
{
    int node = blockIdx.x * 4 + (threadIdx.x >> 6);
    int lane = threadIdx.x & 63;
    if (node >= n) return;
    int s = rp[node], t = rp[node + 1];
    float2 acc = make_float2(0.f, 0.f);
    for (int j = s; j < t; ++j) {
        int id = idxarr[j];
        float2 v = reinterpret_cast<const float2*>(X + (size_t)id * HH)[lane];
        acc.x += v.x; acc.y += v.y;
    }
    reinterpret_cast<float2*>(out + (size_t)node * HH)[lane] = acc;
}

// ---------------------------------------------------------------------------
extern "C" void kernel_launch(void* const* d_in, const int* in_sizes, int n_in,
                              void* d_out, int out_size, void* d_ws, size_t ws_size,
                              hipStream_t stream)
{
    const float* node_feat = (const float*)d_in[0];
    const int*   eidx      = (const int*)d_in[1];
    const float* edge_feat = (const float*)d_in[2];
    const float* W_node    = (const float*)d_in[3];
    const float* b_node    = (const float*)d_in[4];
    const float* W_edge    = (const float*)d_in[5];
    const float* b_edge    = (const float*)d_in[6];
    const float* W_msg     = (const float*)d_in[7];
    const float* b_msg     = (const float*)d_in[8];
    const float* W_ih      = (const float*)d_in[9];
    const float* W_hh      = (const float*)d_in[10];
    const float* b_ih      = (const float*)d_in[11];
    const float* b_hh      = (const float*)d_in[12];

    const int* src = eidx;
    const int* dst = eidx + EE;

    float* out_h = (float*)d_out;               // N x 128
    float* out_e = out_h + (size_t)NN * HH;     // E x 128

    // workspace layout (f32 elements)
    float* A   = (float*)d_ws;                  // h ping      (N x 128)
    float* B   = A + (size_t)NN * HH;           // h pong      (N x 128)
    float* C   = B + (size_t)NN * HH;           // agg_e       (N x 128)
    float* D   = C + (size_t)NN * HH;           // esum / gh   (N x 128)
    float* Eb  = D + (size_t)NN * HH;           // agg         (N x 128)
    float* F   = Eb + (size_t)NN * HH;          // gi          (N x 384)
    int* deg   = (int*)(F + (size_t)NN * 384);  // N
    int* rp    = deg + NN;                      // N+1
    int* cur   = rp + (NN + 1);                 // N
    int* bsum  = cur + NN;                      // 64
    int* eid   = bsum + 64;                     // E
    int* ssrc  = eid + EE;                      // E

    hipMemsetAsync(deg, 0, NN * sizeof(int), stream);

    // h0 = node_feat @ W_node.T + b_node
    k_gemm<32, true, false, false><<<dim3(782, 2), 256, 0, stream>>>(
        node_feat, ND, W_node, ND, b_node, nullptr, nullptr, A, NN, HH);

    // e = edge_feat @ W_edge.T + b_edge  (second output, written directly)
    k_gemm<32, true, false, false><<<dim3(12500, 2), 256, 0, stream>>>(
        edge_feat, ED, W_edge, ED, b_edge, nullptr, nullptr, out_e, EE, HH);

    // CSR build (bucket edges by dst)
    k_hist<<<EE / 256, 256, 0, stream>>>(dst, deg, EE);
    k_scan_block<<<49, 1024, 0, stream>>>(deg, rp, bsum, NN);
    k_scan_tops<<<1, 64, 0, stream>>>(bsum, 49);
    k_scan_add<<<49, 1024, 0, stream>>>(rp, bsum, NN);
    k_cursor<<<196, 256, 0, stream>>>(rp, cur, NN);
    k_bucket<<<EE / 256, 256, 0, stream>>>(src, dst, cur, eid, ssrc, EE);

    // agg_e = segsum(e, dst) @ W_msg_e.T + deg * b_msg   (iteration-invariant)
    k_pull<<<12500, 256, 0, stream>>>(out_e, eid, rp, D, NN);
    k_gemm<32, true, false, true><<<dim3(782, 2), 256, 0, stream>>>(
        D, HH, W_msg + HH, 2 * HH, b_msg, nullptr, deg, C, NN, HH);

    // 3 message-passing + GRU iterations
    const float* hin = A;
    for (int t = 0; t < 3; ++t) {
        float* hout = (t == 2) ? out_h : ((t == 0) ? B : A);
        // gh = segsum(h[src], dst)
        k_pull<<<12500, 256, 0, stream>>>(hin, ssrc, rp, D, NN);
        // agg = gh @ W_msg_h.T + agg_e
        k_gemm<32, false, true, false><<<dim3(782, 2), 256, 0, stream>>>(
            D, HH, W_msg, 2 * HH, nullptr, C, nullptr, Eb, NN, HH);
        // gi = agg @ W_ih.T + b_ih
        k_gemm<32, true, false, false><<<dim3(782, 6), 256, 0, stream>>>(
            Eb, HH, W_ih, HH, b_ih, nullptr, nullptr, F, NN, 384);
        // h = GRU(agg, h)  (fused ghh GEMM + gates)
        k_gru<<<dim3(782, 2), 256, 0, stream>>>(hin, W_hh, b_hh, F, hout, NN);
        hin = hout;
    }
}

// Round 4
// 1661.646 us; speedup vs baseline: 1.1940x; 1.1940x over previous
//
#include <hip/hip_runtime.h>
#include <hip/hip_bf16.h>

#define NN 50000
#define EE 800000
#define ND 64
#define ED 32
#define HH 128

typedef __attribute__((ext_vector_type(8)))  short  bf16x8;
typedef __attribute__((ext_vector_type(4)))  float  f32x4;
typedef __attribute__((ext_vector_type(8)))  ushort u16x8;

// float -> bf16 (round-to-nearest-even), and back
__device__ __forceinline__ ushort f2bf(float f) {
    unsigned u = __float_as_uint(f);
    unsigned r = (u + 0x7FFFu + ((u >> 16) & 1u)) >> 16;
    return (ushort)r;
}
__device__ __forceinline__ float bf2f(ushort h) {
    return __uint_as_float(((unsigned)h) << 16);
}

// ---------------------------------------------------------------------------
// Split-bf16 MFMA GEMM:  Y[.,col] = X[M x K] @ W[rows=col][K-slice].T + opts
// x = hi + lo (bf16 each); acc += hi*hi + hi*lo + lo*hi  (lo*lo ~2^-18 rel, dropped)
// Tile: BM=128, BN=128, BK=32. 4 waves in 2x2; wave tile 64x64 (4x4 frags 16x16).
// GRU mode: acc is h_n pre-bias; gates read from Cm (F: r,z summed / i_n) and
// hprev; writes final h. In-place safe: blocks partition rows.
// ---------------------------------------------------------------------------
template<bool BIAS, bool CMAT, bool DEGB, bool GRU>
__global__ __launch_bounds__(256) void k_mgemm(
    const float* __restrict__ X, int K,
    const float* __restrict__ W, int ldw,
    const float* __restrict__ bias,
    const float* __restrict__ Cm, int ldc,
    const int* __restrict__ deg,
    const float* __restrict__ hprev,
    float* __restrict__ Y, int ldy, int M)
{
    __shared__ ushort XH[128][40];  // +8 pad: 80B row stride, ~2-way banks (free)
    __shared__ ushort XL[128][40];
    __shared__ ushort WH[128][40];
    __shared__ ushort WL[128][40];

    const int m0 = blockIdx.x * 128;
    const int n0 = blockIdx.y * 128;
    const int tid  = threadIdx.x;
    const int lane = tid & 63;
    const int wave = tid >> 6;
    const int wm = wave >> 1, wn = wave & 1;   // wave grid 2x2
    const int lr = lane & 15;                  // frag row/col
    const int lg = lane >> 4;                  // k-group (0..3)

    f32x4 acc[4][4];
    #pragma unroll
    for (int i = 0; i < 4; ++i)
        #pragma unroll
        for (int j = 0; j < 4; ++j)
            acc[i][j] = (f32x4){0.f, 0.f, 0.f, 0.f};

    const int srow  = tid >> 1;     // 0..127 (staging row)
    const int shalf = tid & 1;      // which 16-float half of the 32-wide K slab

    for (int k0 = 0; k0 < K; k0 += 32) {
        // ---- stage X tile (128 x 32 f32 -> hi/lo bf16) ----
        {
            float v[16];
            int gr = m0 + srow;
            if (gr < M) {
                const float* p = X + (size_t)gr * K + k0 + shalf * 16;
                float4 a = *reinterpret_cast<const float4*>(p);
                float4 b = *reinterpret_cast<const float4*>(p + 4);
                float4 c = *reinterpret_cast<const float4*>(p + 8);
                float4 d = *reinterpret_cast<const float4*>(p + 12);
                v[0]=a.x; v[1]=a.y; v[2]=a.z; v[3]=a.w;
                v[4]=b.x; v[5]=b.y; v[6]=b.z; v[7]=b.w;
                v[8]=c.x; v[9]=c.y; v[10]=c.z; v[11]=c.w;
                v[12]=d.x; v[13]=d.y; v[14]=d.z; v[15]=d.w;
            } else {
                #pragma unroll
                for (int i = 0; i < 16; ++i) v[i] = 0.f;
            }
            u16x8 h0, h1, l0, l1;
            #pragma unroll
            for (int i = 0; i < 8; ++i) {
                ushort h = f2bf(v[i]);      h0[i] = h; l0[i] = f2bf(v[i] - bf2f(h));
            }
            #pragma unroll
            for (int i = 0; i < 8; ++i) {
                ushort h = f2bf(v[8 + i]);  h1[i] = h; l1[i] = f2bf(v[8 + i] - bf2f(h));
            }
            *reinterpret_cast<u16x8*>(&XH[srow][shalf * 16])     = h0;
            *reinterpret_cast<u16x8*>(&XH[srow][shalf * 16 + 8]) = h1;
            *reinterpret_cast<u16x8*>(&XL[srow][shalf * 16])     = l0;
            *reinterpret_cast<u16x8*>(&XL[srow][shalf * 16 + 8]) = l1;
        }
        // ---- stage W tile (rows n0..n0+127 of W; caller guarantees validity) ----
        {
            const float* p = W + (size_t)(n0 + srow) * ldw + k0 + shalf * 16;
            float4 a = *reinterpret_cast<const float4*>(p);
            float4 b = *reinterpret_cast<const float4*>(p + 4);
            float4 c = *reinterpret_cast<const float4*>(p + 8);
            float4 d = *reinterpret_cast<const float4*>(p + 12);
            float v[16] = {a.x,a.y,a.z,a.w, b.x,b.y,b.z,b.w,
                           c.x,c.y,c.z,c.w, d.x,d.y,d.z,d.w};
            u16x8 h0, h1, l0, l1;
            #pragma unroll
            for (int i = 0; i < 8; ++i) {
                ushort h = f2bf(v[i]);      h0[i] = h; l0[i] = f2bf(v[i] - bf2f(h));
            }
            #pragma unroll
            for (int i = 0; i < 8; ++i) {
                ushort h = f2bf(v[8 + i]);  h1[i] = h; l1[i] = f2bf(v[8 + i] - bf2f(h));
            }
            *reinterpret_cast<u16x8*>(&WH[srow][shalf * 16])     = h0;
            *reinterpret_cast<u16x8*>(&WH[srow][shalf * 16 + 8]) = h1;
            *reinterpret_cast<u16x8*>(&WL[srow][shalf * 16])     = l0;
            *reinterpret_cast<u16x8*>(&WL[srow][shalf * 16 + 8]) = l1;
        }
        __syncthreads();

        // ---- fragments + 3-product MFMA ----
        bf16x8 ah[4], al[4], bh[4], bl[4];
        #pragma unroll
        for (int mf = 0; mf < 4; ++mf) {
            ah[mf] = *reinterpret_cast<const bf16x8*>(&XH[wm * 64 + mf * 16 + lr][lg * 8]);
            al[mf] = *reinterpret_cast<const bf16x8*>(&XL[wm * 64 + mf * 16 + lr][lg * 8]);
        }
        #pragma unroll
        for (int nf = 0; nf < 4; ++nf) {
            bh[nf] = *reinterpret_cast<const bf16x8*>(&WH[wn * 64 + nf * 16 + lr][lg * 8]);
            bl[nf] = *reinterpret_cast<const bf16x8*>(&WL[wn * 64 + nf * 16 + lr][lg * 8]);
        }
        #pragma unroll
        for (int mf = 0; mf < 4; ++mf)
            #pragma unroll
            for (int nf = 0; nf < 4; ++nf) {
                acc[mf][nf] = __builtin_amdgcn_mfma_f32_16x16x32_bf16(ah[mf], bh[nf], acc[mf][nf], 0, 0, 0);
                acc[mf][nf] = __builtin_amdgcn_mfma_f32_16x16x32_bf16(ah[mf], bl[nf], acc[mf][nf], 0, 0, 0);
                acc[mf][nf] = __builtin_amdgcn_mfma_f32_16x16x32_bf16(al[mf], bh[nf], acc[mf][nf], 0, 0, 0);
            }
        __syncthreads();
    }

    // ---- epilogue: D col = lane&15, row = (lane>>4)*4 + reg (m89-verified) ----
    #pragma unroll
    for (int mf = 0; mf < 4; ++mf) {
        #pragma unroll
        for (int nf = 0; nf < 4; ++nf) {
            int col = n0 + wn * 64 + nf * 16 + lr;
            int rowb = m0 + wm * 64 + mf * 16 + lg * 4;
            #pragma unroll
            for (int i = 0; i < 4; ++i) {
                int r = rowb + i;
                if (r >= M) continue;
                float v = acc[mf][nf][i];
                if (BIAS) v += DEGB ? bias[col] * (float)deg[r] : bias[col];
                if (GRU) {
                    // v = h_n; F holds [i_r+h_r | i_z+h_z | i_n] (biases included)
                    float fr = Cm[(size_t)r * ldc + col];
                    float fz = Cm[(size_t)r * ldc + col + 128];
                    float fn = Cm[(size_t)r * ldc + col + 256];
                    float rr = 1.f / (1.f + expf(-fr));
                    float zz = 1.f / (1.f + expf(-fz));
                    float nn = tanhf(fn + rr * v);
                    v = (1.f - zz) * nn + zz * hprev[(size_t)r * HH + col];
                } else if (CMAT) {
                    v += Cm[(size_t)r * ldc + col];
                }
                Y[(size_t)r * ldy + col] = v;
            }
        }
    }
}

// ---------------------------------------------------------------------------
// CSR build: histogram, scan, cursor copy, bucket scatter (unchanged, passed R1)
// ---------------------------------------------------------------------------
__global__ void k_hist(const int* __restrict__ dst, int* __restrict__ deg, int n) {
    int e = blockIdx.x * 256 + threadIdx.x;
    if (e < n) atomicAdd(&deg[dst[e]], 1);
}

__global__ __launch_bounds__(1024) void k_scan_block(
    const int* __restrict__ deg, int* __restrict__ rp, int* __restrict__ bsum, int n)
{
    __shared__ int s[1024];
    int i = blockIdx.x * 1024 + threadIdx.x;
    s[threadIdx.x] = (i < n) ? deg[i] : 0;
    __syncthreads();
    for (int off = 1; off < 1024; off <<= 1) {
        int t = (threadIdx.x >= (unsigned)off) ? s[threadIdx.x - off] : 0;
        __syncthreads();
        s[threadIdx.x] += t;
        __syncthreads();
    }
    if (i < n) rp[i + 1] = s[threadIdx.x];
    if (threadIdx.x == 1023) bsum[blockIdx.x] = s[1023];
}

__global__ void k_scan_tops(int* bsum, int nb) {
    if (threadIdx.x == 0 && blockIdx.x == 0) {
        int run = 0;
        for (int b = 0; b < nb; ++b) { int v = bsum[b]; bsum[b] = run; run += v; }
    }
}

__global__ __launch_bounds__(1024) void k_scan_add(int* rp, const int* __restrict__ bsum, int n) {
    int i = blockIdx.x * 1024 + threadIdx.x;
    if (i < n) rp[i + 1] += bsum[blockIdx.x];
    if (i == 0) rp[0] = 0;
}

__global__ void k_cursor(const int* __restrict__ rp, int* __restrict__ cur, int n) {
    int i = blockIdx.x * 256 + threadIdx.x;
    if (i < n) cur[i] = rp[i];
}

__global__ void k_bucket(const int* __restrict__ src, const int* __restrict__ dst,
                         int* __restrict__ cur, int* __restrict__ eid,
                         int* __restrict__ ssrc, int n)
{
    int e = blockIdx.x * 256 + threadIdx.x;
    if (e < n) {
        int d = dst[e];
        int p = atomicAdd(&cur[d], 1);
        eid[p] = e;
        ssrc[p] = src[e];
    }
}

// ---------------------------------------------------------------------------
// Pull-reduce: out[d][:] = sum over CSR range of X[idx[j]][:]  (128 f32 cols)
// one wave per node; lane holds float2 (2 cols)
// ---------------------------------------------------------------------------
__global__ __launch_bounds__(256) void k_pull(
    const float* __restrict__ X, const int* __restrict__ idxarr,
    const int* __restrict__ rp, float* __restrict__ out, int n)
{
    int node = blockIdx.x * 4 + (threadIdx.x >> 6);
    int lane = threadIdx.x & 63;
    if (node >= n) return;
    int s = rp[node], t = rp[node + 1];
    float2 acc = make_float2(0.f, 0.f);
    for (int j = s; j < t; ++j) {
        int id = idxarr[j];
        float2 v = reinterpret_cast<const float2*>(X + (size_t)id * HH)[lane];
        acc.x += v.x; acc.y += v.y;
    }
    reinterpret_cast<float2*>(out + (size_t)node * HH)[lane] = acc;
}

// ---------------------------------------------------------------------------
extern "C" void kernel_launch(void* const* d_in, const int* in_sizes, int n_in,
                              void* d_out, int out_size, void* d_ws, size_t ws_size,
                              hipStream_t stream)
{
    const float* node_feat = (const float*)d_in[0];
    const int*   eidx      = (const int*)d_in[1];
    const float* edge_feat = (const float*)d_in[2];
    const float* W_node    = (const float*)d_in[3];
    const float* b_node    = (const float*)d_in[4];
    const float* W_edge    = (const float*)d_in[5];
    const float* b_edge    = (const float*)d_in[6];
    const float* W_msg     = (const float*)d_in[7];
    const float* b_msg     = (const float*)d_in[8];
    const float* W_ih      = (const float*)d_in[9];
    const float* W_hh      = (const float*)d_in[10];
    const float* b_ih      = (const float*)d_in[11];
    const float* b_hh      = (const float*)d_in[12];
    (void)in_sizes; (void)n_in; (void)out_size; (void)ws_size;

    const int* src = eidx;
    const int* dst = eidx + EE;

    float* out_h = (float*)d_out;               // N x 128
    float* out_e = out_h + (size_t)NN * HH;     // E x 128

    // workspace layout (f32 elements) — high water ~186 MB (< R1-proven 212 MB)
    float* A   = (float*)d_ws;                  // h (in-place across iters) N x 128
    float* C   = A + (size_t)NN * HH;           // agg_e                     N x 128
    float* D   = C + (size_t)NN * HH;           // pull tmp                  N x 128
    float* Eb  = D + (size_t)NN * HH;           // agg                       N x 128
    float* F   = Eb + (size_t)NN * HH;          // gi / gate accum           N x 384
    int* deg   = (int*)(F + (size_t)NN * 384);  // N
    int* rp    = deg + NN;                      // N+1
    int* cur   = rp + (NN + 1);                 // N
    int* bsum  = cur + NN;                      // 64
    int* eid   = bsum + 64;                     // E
    int* ssrc  = eid + EE;                      // E

    hipMemsetAsync(deg, 0, NN * sizeof(int), stream);

    // h0 = node_feat @ W_node.T + b_node    (M=50000, K=64, Ncols=128)
    k_mgemm<true, false, false, false><<<dim3(391, 1), 256, 0, stream>>>(
        node_feat, ND, W_node, ND, b_node, nullptr, 0, nullptr, nullptr, A, HH, NN);

    // e = edge_feat @ W_edge.T + b_edge     (M=800000, K=32, Ncols=128)
    k_mgemm<true, false, false, false><<<dim3(6250, 1), 256, 0, stream>>>(
        edge_feat, ED, W_edge, ED, b_edge, nullptr, 0, nullptr, nullptr, out_e, HH, EE);

    // CSR build (bucket edges by dst)
    k_hist<<<EE / 256, 256, 0, stream>>>(dst, deg, EE);
    k_scan_block<<<49, 1024, 0, stream>>>(deg, rp, bsum, NN);
    k_scan_tops<<<1, 64, 0, stream>>>(bsum, 49);
    k_scan_add<<<49, 1024, 0, stream>>>(rp, bsum, NN);
    k_cursor<<<196, 256, 0, stream>>>(rp, cur, NN);
    k_bucket<<<EE / 256, 256, 0, stream>>>(src, dst, cur, eid, ssrc, EE);

    // agg_e = segsum(e, dst) @ W_msg_e.T + deg * b_msg   (iteration-invariant)
    k_pull<<<12500, 256, 0, stream>>>(out_e, eid, rp, D, NN);
    k_mgemm<true, false, true, false><<<dim3(391, 1), 256, 0, stream>>>(
        D, HH, W_msg + HH, 2 * HH, b_msg, nullptr, 0, deg, nullptr, C, HH, NN);

    // 3 message-passing + GRU iterations (h lives in A, updated in place)
    for (int t = 0; t < 3; ++t) {
        float* hout = (t == 2) ? out_h : A;
        // D = segsum(h[src], dst)
        k_pull<<<12500, 256, 0, stream>>>(A, ssrc, rp, D, NN);
        // agg = D @ W_msg_h.T + agg_e
        k_mgemm<false, true, false, false><<<dim3(391, 1), 256, 0, stream>>>(
            D, HH, W_msg, 2 * HH, nullptr, C, HH, nullptr, nullptr, Eb, HH, NN);
        // F = gi = agg @ W_ih.T + b_ih                       (Ncols=384)
        k_mgemm<true, false, false, false><<<dim3(391, 3), 256, 0, stream>>>(
            Eb, HH, W_ih, HH, b_ih, nullptr, 0, nullptr, nullptr, F, 384, NN);
        // F[:, 0:256] += h @ W_hh[0:256].T + b_hh[0:256]     (r,z gate sums)
        k_mgemm<true, true, false, false><<<dim3(391, 2), 256, 0, stream>>>(
            A, HH, W_hh, HH, b_hh, F, 384, nullptr, nullptr, F, 384, NN);
        // h_n GEMM + fused gates: hout = (1-z)*n + z*h
        k_mgemm<true, true, false, true><<<dim3(391, 1), 256, 0, stream>>>(
            A, HH, W_hh + 256 * HH, HH, b_hh + 256, F, 384, nullptr, A, hout, HH, NN);
    }
}